// Round 1
// baseline (234.614 us; speedup 1.0000x reference)
//
#include <hip/hip_runtime.h>
#include <math.h>

#define NQ    14
#define DIM   16384
#define DEPTH 4

typedef float2 c32;

__device__ __forceinline__ c32 cmul(c32 a, c32 b) {
    return make_float2(a.x*b.x - a.y*b.y, a.x*b.y + a.y*b.x);
}
__device__ __forceinline__ c32 cadd(c32 a, c32 b) { return make_float2(a.x+b.x, a.y+b.y); }
__device__ __forceinline__ c32 csc(float s, c32 a) { return make_float2(s*a.x, s*a.y); }

// LDS swizzle: XOR high bits into bank bits so every pass's ds_read_b64 spreads
// 64 lanes across all 16 bank-pairs (4 lanes/pair = b64 optimum).
__device__ __forceinline__ int sw(int e) { return e ^ ((e >> 6) & 0xF); }

// CZ chain sign: qubit w <-> flat bit (13-w); adjacent qubit pairs are adjacent
// flat bits, so parity = popc(e & (e>>1)) & 1.
__device__ __forceinline__ float czsgn(int e) {
    return (__popc(e & (e >> 1)) & 1) ? -1.0f : 1.0f;
}

// Per-pass element mapping. Thread t (10 bits) handles 16 amplitudes (loop l).
// Pass 0: gates on qubits 0-3   (flat bits 13..10 = l bits 3..0)
// Pass 1: gates on qubits 4-7   (flat bits  9..6  = l bits 3..0)
// Pass 2: gates on qubits 8-11  (flat bits  5..2  = l bits 3..0)
// Pass 3: gates on qubits 12,13 (flat bits  1..0  = l bits 1..0; l bits 3..2 = e bits 13..12)
// Lane bits (t0..t5) are placed so swizzled bank bits vary fully across a wave.
template<int PASS>
__device__ __forceinline__ int emap(int t, int l) {
    if (PASS == 0) return (l << 10) | t;
    if (PASS == 1) return ((t >> 6) << 10) | (l << 6) | (t & 63);
    if (PASS == 2) return ((t >> 2) << 6) | (l << 2) | (t & 3);
    return ((l >> 2) << 12) | (t << 2) | (l & 3);
}

template<int PASS>
__device__ __forceinline__ void do_pass(c32* st, const c32 (*gl)[4], int t,
                                        bool mulsign, bool finalp, float* acc)
{
    c32 a[16];
    int idx[16];
    #pragma unroll
    for (int l = 0; l < 16; ++l) {
        int e = emap<PASS>(t, l);
        idx[l] = sw(e);
        a[l] = st[idx[l]];
    }
    if (mulsign) {  // fused CZ sign from the previous layer
        #pragma unroll
        for (int l = 0; l < 16; ++l) {
            float s = czsgn(emap<PASS>(t, l));
            a[l].x *= s; a[l].y *= s;
        }
    }
    constexpr int NGATE = (PASS == 3) ? 2 : 4;
    constexpr int QBASE = 4 * PASS;
    #pragma unroll
    for (int g = 0; g < NGATE; ++g) {
        const int mask = (PASS == 3) ? (2 >> g) : (8 >> g);
        c32 u00 = gl[QBASE + g][0];
        c32 u01 = gl[QBASE + g][1];
        c32 u10 = gl[QBASE + g][2];
        c32 u11 = gl[QBASE + g][3];
        #pragma unroll
        for (int l = 0; l < 16; ++l) {
            if (l & mask) continue;
            const int j = l | mask;
            c32 x = a[l], y = a[j];
            a[l] = cadd(cmul(u00, x), cmul(u01, y));
            a[j] = cadd(cmul(u10, x), cmul(u11, y));
        }
    }
    if (!finalp) {
        #pragma unroll
        for (int l = 0; l < 16; ++l) st[idx[l]] = a[l];
    } else {
        // fused probability reduction: acc[w] += ±|a|^2 per Z_SIGNS
        #pragma unroll
        for (int l = 0; l < 16; ++l) {
            int e = emap<PASS>(t, l);
            float p = a[l].x*a[l].x + a[l].y*a[l].y;
            #pragma unroll
            for (int w = 0; w < NQ; ++w)
                acc[w] += ((e >> (13 - w)) & 1) ? -p : p;
        }
    }
}

__global__ __launch_bounds__(1024, 1)
void qlg_kernel(const float* __restrict__ cond,
                const float* __restrict__ Wenc,
                const float* __restrict__ benc,
                const float* __restrict__ wts,
                float* __restrict__ out)
{
    __shared__ c32 st[DIM];                 // 128 KB state (swizzled index)
    __shared__ c32 gates[DEPTH][NQ][4];     // variational 2x2 gate matrices
    __shared__ c32 qv[NQ][2];               // per-wire product-state vectors
    __shared__ c32 Phi[128];                // partial product, qubits 0..6
    __shared__ c32 Plo[128];                // partial product, qubits 7..13
    __shared__ float embS[NQ];
    __shared__ float wred[16][NQ];
    __shared__ float lat[NQ];

    const int b = blockIdx.x;
    const int t = threadIdx.x;

    // ---- stage 1: embedding (SiLU) + gate matrices ----
    if (t < NQ) {
        float s = benc[t];
        #pragma unroll
        for (int k = 0; k < NQ; ++k) s += cond[b*NQ + k] * Wenc[t*NQ + k];
        embS[t] = s / (1.0f + __expf(-s));
    }
    if (t >= 64 && t < 64 + DEPTH*NQ) {
        const int gi = t - 64;
        const int d = gi / NQ, w = gi % NQ;
        const float p0 = wts[(d*NQ + w)*3 + 0];
        const float p1 = wts[(d*NQ + w)*3 + 1];
        const float p2 = wts[(d*NQ + w)*3 + 2];
        float s0, c0, s1, c1, s2, c2;
        sincosf(0.5f*p0, &s0, &c0);
        sincosf(0.5f*p1, &s1, &c1);
        sincosf(0.5f*p2, &s2, &c2);
        // U = RY(p2) * RX(p1) * RZ(p0)
        c32 e0  = make_float2(c0, -s0);     // exp(-i p0/2)
        c32 e0c = make_float2(c0,  s0);
        c32 is1 = make_float2(0.f, -s1);    // -i sin(p1/2)
        c32 m00 = csc(c1, e0);
        c32 m01 = cmul(is1, e0c);
        c32 m10 = cmul(is1, e0);
        c32 m11 = csc(c1, e0c);
        gates[d][w][0] = cadd(csc(c2, m00), csc(-s2, m10));
        gates[d][w][1] = cadd(csc(c2, m01), csc(-s2, m11));
        gates[d][w][2] = cadd(csc(s2, m00), csc( c2, m10));
        gates[d][w][3] = cadd(csc(s2, m01), csc( c2, m11));
    }
    __syncthreads();

    // ---- stage 2: per-wire 2-vectors after encoding + layer 0 ----
    if (t < NQ) {
        float v = embS[t];
        float s, c;
        sincosf(0.5f*v, &s, &c);
        c32 a0 = make_float2(c*c,  s*s);    // (RY RX)|0> component 0
        c32 a1 = make_float2(s*c, -s*c);    // component 1
        c32 u00 = gates[0][t][0], u01 = gates[0][t][1];
        c32 u10 = gates[0][t][2], u11 = gates[0][t][3];
        qv[t][0] = cadd(cmul(u00, a0), cmul(u01, a1));
        qv[t][1] = cadd(cmul(u10, a0), cmul(u11, a1));
    }
    __syncthreads();

    // ---- stage 3: partial-product tables ----
    if (t < 128) {
        c32 p = qv[0][(t >> 6) & 1];
        #pragma unroll
        for (int w = 1; w <= 6; ++w) p = cmul(p, qv[w][(t >> (6 - w)) & 1]);
        Phi[t] = p;
    } else if (t < 256) {
        const int j = t - 128;
        c32 p = qv[7][(j >> 6) & 1];
        #pragma unroll
        for (int w = 8; w <= 13; ++w) p = cmul(p, qv[w][(j >> (13 - w)) & 1]);
        Plo[j] = p;
    }
    __syncthreads();

    // ---- stage 4: build product state, fusing CZ after layer 0 ----
    #pragma unroll
    for (int l = 0; l < 16; ++l) {
        const int e = (l << 10) | t;
        c32 v = cmul(Phi[e >> 7], Plo[e & 127]);
        st[sw(e)] = csc(czsgn(e), v);
    }
    __syncthreads();

    // ---- stage 5: layers 1..3 ----
    float acc[NQ];
    #pragma unroll
    for (int w = 0; w < NQ; ++w) acc[w] = 0.f;

    for (int d = 1; d < DEPTH; ++d) {
        const c32 (*gl)[4] = gates[d];
        const bool signA = (d >= 2);          // CZ of layer d-1 fused into pass 0 load
        const bool fin   = (d == DEPTH - 1);  // last pass fuses the reduction
        do_pass<0>(st, gl, t, signA, false, acc);
        __syncthreads();
        do_pass<1>(st, gl, t, false, false, acc);
        __syncthreads();
        do_pass<2>(st, gl, t, false, false, acc);
        __syncthreads();
        do_pass<3>(st, gl, t, false, fin, acc);
        if (!fin) __syncthreads();
    }
    // (CZ after the last layer is a ±1 diagonal: |psi|^2 unchanged — skipped)

    // ---- stage 6: reduce 1024 threads -> 14 expectations, layernorm ----
    #pragma unroll
    for (int w = 0; w < NQ; ++w) {
        float v = acc[w];
        #pragma unroll
        for (int off = 32; off > 0; off >>= 1) v += __shfl_down(v, off, 64);
        acc[w] = v;
    }
    const int lane = t & 63, wv = t >> 6;
    if (lane == 0) {
        #pragma unroll
        for (int w = 0; w < NQ; ++w) wred[wv][w] = acc[w];
    }
    __syncthreads();
    if (t < NQ) {
        float s = 0.f;
        #pragma unroll
        for (int k = 0; k < 16; ++k) s += wred[k][t];
        lat[t] = s;
    }
    __syncthreads();
    if (t < NQ) {
        float mu = 0.f;
        #pragma unroll
        for (int k = 0; k < NQ; ++k) mu += lat[k];
        mu *= (1.0f / NQ);
        float var = 0.f;
        #pragma unroll
        for (int k = 0; k < NQ; ++k) { float dv = lat[k] - mu; var += dv*dv; }
        var *= (1.0f / NQ);
        out[b*NQ + t] = (lat[t] - mu) * rsqrtf(var + 1e-5f);
    }
}

extern "C" void kernel_launch(void* const* d_in, const int* in_sizes, int n_in,
                              void* d_out, int out_size, void* d_ws, size_t ws_size,
                              hipStream_t stream)
{
    (void)n_in; (void)d_ws; (void)ws_size; (void)out_size;
    const float* cond = (const float*)d_in[0];
    const float* Wenc = (const float*)d_in[1];
    const float* benc = (const float*)d_in[2];
    const float* wts  = (const float*)d_in[3];
    float* out = (float*)d_out;
    const int B = in_sizes[0] / NQ;   // 256
    qlg_kernel<<<dim3(B), dim3(1024), 0, stream>>>(cond, Wenc, benc, wts, out);
}